// Round 12
// baseline (284.972 us; speedup 1.0000x reference)
//
#include <hip/hip_runtime.h>

// RbfNet on MI355X — round 12:
// (a) conv_gather: 2 waves per node (edge list split [0,24)/[24,48), LDS combine).
//     Poisson(16) degrees -> old E[serial 16-edge batch rounds] ~1.5; split -> ~1.0,
//     with 2x waves for the memory system to interleave.
// (b) prep_t fused into conv_gather layer-2 epilogue (butterfly-reduced T[i][16]).
// Structure from r11: UL[j] = [x_j @ cW (p-major, 512) | x_j @ fW (64)] dense MFMA GEMM,
// then conv(x)[i] = sum_e w0*U[j,p] + w1*U[j,p+1]  (2 loads + 2 FMA per edge).
// Edge record (4B): j(15b) | p(3b) | round(w0*16383)(14b); w1 = 1-w0. Self-edges dropped.

#define CAP 48

typedef __attribute__((ext_vector_type(8))) short short8;
typedef __attribute__((ext_vector_type(4))) short short4v;
typedef __attribute__((ext_vector_type(4))) float f32x4;

__device__ __forceinline__ short bf16s(float f) {   // fp32 -> bf16 RNE
  unsigned u = __float_as_uint(f);
  return (short)((u + 0x7FFF + ((u >> 16) & 1)) >> 16);
}
__device__ __forceinline__ float b2f(unsigned short s) {
  return __uint_as_float(((unsigned)s) << 16);
}

// ---------- edge-bucket build ----------
__global__ void fill_kernel(const float* __restrict__ dist,
                            const int* __restrict__ fi, const int* __restrict__ fj,
                            int* __restrict__ cnt, int* __restrict__ jw, int nE) {
  int e = blockIdx.x * blockDim.x + threadIdx.x;
  if (e >= nE) return;
  int i = fi[e], j = fj[e];
  if (i == j) return;                    // centerIgnore
  float d = fminf(1.0f, fmaxf(-1.0f, dist[e]));
  float u = (d + 1.0f) * 3.5f;           // hat centers: spacing 2/7
  int p = min((int)u, 6);
  float w0 = 1.0f - (u - (float)p);
  int wq = (int)(w0 * 16383.0f + 0.5f);
  int pos = atomicAdd(&cnt[i], 1);
  if (pos < CAP)
    jw[(size_t)i * CAP + pos] = j | (p << 15) | (wq << 18);
}

// ---------- prep: WTul[col][ch] bf16; col<512: cW[p=col>>6][ch][co=col&63]; col>=512: fW[ch][col-512]
__global__ void prep_wtul(const float* __restrict__ cW1, const float* __restrict__ fW1,
                          const float* __restrict__ cW2, const float* __restrict__ fW2,
                          short* __restrict__ wt1, short* __restrict__ wt2) {
  int idx = blockIdx.x * blockDim.x + threadIdx.x;
  if (idx >= 2 * 576 * 64) return;
  int sel = idx / (576 * 64);
  int r = idx - sel * (576 * 64);
  int col = r >> 6, ch = r & 63;
  const float* cW = sel ? cW2 : cW1;
  const float* fW = sel ? fW2 : fW1;
  float v;
  if (col < 512) {
    int p = col >> 6, co = col & 63;
    v = cW[((size_t)p * 64 + ch) * 64 + co];
  } else {
    v = fW[(size_t)ch * 64 + (col - 512)];
  }
  (sel ? wt2 : wt1)[(size_t)col * 64 + ch] = bf16s(v);
}

// ---------- layer 0: wave per node, lane-parallel edges, LDS fp32 atomics ----------
__global__ __launch_bounds__(256) void layer0_kernel(
    const float* __restrict__ X,      // [n,4] fp32
    const int* __restrict__ cnt, const int* __restrict__ jw,
    const float* __restrict__ cW0,    // [8*4*32]
    const float* __restrict__ cb0,
    const float* __restrict__ fW0,    // [4*32]
    const float* __restrict__ fb0,
    unsigned short* __restrict__ ansc0, int n) {    // [n,64] bf16 out
  __shared__ float sW[1024];
  __shared__ float sF[128];
  __shared__ float sB[64];
  __shared__ float sacc[4][32];
  for (int idx = threadIdx.x; idx < 1024; idx += 256) sW[idx] = cW0[idx];
  for (int idx = threadIdx.x; idx < 128; idx += 256) sF[idx] = fW0[idx];
  if (threadIdx.x < 32) sB[threadIdx.x] = cb0[threadIdx.x];
  else if (threadIdx.x < 64) sB[threadIdx.x] = fb0[threadIdx.x - 32];
  const int w = threadIdx.x >> 6;
  const int lane = threadIdx.x & 63;
  const int i = blockIdx.x * 4 + w;
  const bool valid = (i < n);
  if (valid && lane < 32) sacc[w][lane] = 0.0f;
  __syncthreads();
  if (valid && lane < min(cnt[i], CAP)) {   // lane = edge index
    int v = jw[(size_t)i * CAP + lane];
    int j = v & 0x7FFF;
    int p = (v >> 15) & 7;
    float w0 = (float)((unsigned)v >> 18) * (1.0f / 16383.0f);
    float w1 = 1.0f - w0;
    float4 x = *(const float4*)(X + (size_t)j * 4);
    atomicAdd(&sacc[w][p * 4 + 0], w0 * x.x);
    atomicAdd(&sacc[w][p * 4 + 1], w0 * x.y);
    atomicAdd(&sacc[w][p * 4 + 2], w0 * x.z);
    atomicAdd(&sacc[w][p * 4 + 3], w0 * x.w);
    atomicAdd(&sacc[w][(p + 1) * 4 + 0], w1 * x.x);
    atomicAdd(&sacc[w][(p + 1) * 4 + 1], w1 * x.y);
    atomicAdd(&sacc[w][(p + 1) * 4 + 2], w1 * x.z);
    atomicAdd(&sacc[w][(p + 1) * 4 + 3], w1 * x.w);
  }
  __syncthreads();
  if (!valid) return;
  const float4 xi = *(const float4*)(X + (size_t)i * 4);
  float v;
  if (lane < 32) {                    // lin -> channels 0..31
    v = sB[32 + lane];
    v = fmaf(xi.x, sF[0 * 32 + lane], v);
    v = fmaf(xi.y, sF[1 * 32 + lane], v);
    v = fmaf(xi.z, sF[2 * 32 + lane], v);
    v = fmaf(xi.w, sF[3 * 32 + lane], v);
  } else {                            // conv -> channels 32..63
    const int cc = lane - 32;
    v = sB[cc];
    #pragma unroll
    for (int k = 0; k < 32; ++k)
      v = fmaf(sacc[w][k], sW[k * 32 + cc], v);
  }
  ansc0[(size_t)i * 64 + lane] = (unsigned short)bf16s(fmaxf(v, 0.0f));
}

// ---------- dense MFMA GEMM: UL[n,576] = Xb[n,64] @ WTul^T ----------
__global__ __launch_bounds__(256) void gemm_ul(
    const unsigned short* __restrict__ Xb,  // [n,64] bf16
    const short* __restrict__ WTul,         // [576,64] bf16 (L2-resident)
    unsigned short* __restrict__ UL, int n) {
  __shared__ short sUL[16 * 584];
  const int lane = threadIdx.x & 63;
  const int w = threadIdx.x >> 6;
  const int mrow = lane & 15;
  const int quad = lane >> 4;
  const int nodeBase = blockIdx.x * 16;
  const int bnode = min(nodeBase + mrow, n - 1);
  const unsigned short* bBase = Xb + (size_t)bnode * 64 + quad * 8;
  short8 b0 = *(const short8*)(bBase);
  short8 b1 = *(const short8*)(bBase + 32);
  #pragma unroll
  for (int t = 0; t < 9; ++t) {
    const int ct = w * 9 + t;
    const short* aBase = WTul + (size_t)(ct * 16 + mrow) * 64 + quad * 8;
    short8 a0 = *(const short8*)(aBase);
    short8 a1 = *(const short8*)(aBase + 32);
    f32x4 acc = {0, 0, 0, 0};
    acc = __builtin_amdgcn_mfma_f32_16x16x32_bf16(a0, b0, acc, 0, 0, 0);
    acc = __builtin_amdgcn_mfma_f32_16x16x32_bf16(a1, b1, acc, 0, 0, 0);
    short4v pk;
    #pragma unroll
    for (int reg = 0; reg < 4; ++reg) pk[reg] = bf16s(acc[reg]);
    *(short4v*)(sUL + mrow * 584 + ct * 16 + quad * 4) = pk;
  }
  __syncthreads();
  const int r = threadIdx.x >> 4;
  const int c0 = threadIdx.x & 15;
  if (nodeBase + r < n) {
    unsigned short* dst = UL + (size_t)(nodeBase + r) * 576;
    #pragma unroll
    for (int chunk = c0; chunk < 72; chunk += 16)
      *(short8*)(dst + chunk * 8) = *(const short8*)(sUL + r * 584 + chunk * 8);
  }
}

// ---------- conv gather: 2 waves per node; per edge 1 dword decode + 2 loads + 2 FMA ----------
// Block = 256 (4 waves) = 2 nodes. Wave pair (half 0/1) splits edges [0,24)/[24,48);
// half-0 parks its partial in LDS, half-1 combines + epilogue (+optional fused T).
template <bool HAS_RES, bool STORE_ANS, bool COMPUTE_T>
__global__ __launch_bounds__(256) void conv_gather(
    const unsigned short* __restrict__ UL,  // [n,576] bf16
    const int* __restrict__ cnt, const int* __restrict__ jw,
    const float* __restrict__ cb, const float* __restrict__ fb,
    const float* __restrict__ resid,        // fp32 [n,64] or null
    const float* __restrict__ cW3,          // [8,64,2] (only if COMPUTE_T)
    float* __restrict__ T,                  // [n,16] fp32 (only if COMPUTE_T)
    float* __restrict__ outAns,             // fp32 [n,64] or null
    unsigned short* __restrict__ outAnsc, int n) {  // bf16 [n,64]
  __shared__ float sacc[2][64];
  const int lane = threadIdx.x & 63;
  const int w = threadIdx.x >> 6;
  const int nl = w >> 1, half = w & 1;
  const int i = blockIdx.x * 2 + nl;
  const bool valid = (i < n);
  float acc = 0.0f;
  int span = 0;
  if (valid) {
    const int m = min(cnt[i], CAP);
    span = min(max(m - half * 24, 0), 24);
    // lane q (<24) holds record half*24+q of node i's row
    int rec = jw[(size_t)i * CAP + half * 24 + (lane < 24 ? lane : 0)];
    for (int q0 = 0; q0 < span; q0 += 16) {
      float u0[16], u1[16], w0s[16];
      #pragma unroll
      for (int k = 0; k < 16; ++k) {        // issue all 32 loads before consuming
        int v = __builtin_amdgcn_readlane(rec, (q0 + k) < 24 ? (q0 + k) : 0);
        int j = min(v & 0x7FFF, n - 1);     // clamp garbage slots in-bounds
        int p = (v >> 15) & 7;
        w0s[k] = (float)((unsigned)v >> 18) * (1.0f / 16383.0f);
        const unsigned short* base = UL + (size_t)j * 576 + p * 64 + lane;
        u0[k] = b2f(base[0]);
        u1[k] = b2f(base[64]);
      }
      #pragma unroll
      for (int k = 0; k < 16; ++k) {
        bool ok = (q0 + k < span);
        float w0 = ok ? w0s[k] : 0.0f;
        float w1 = ok ? (1.0f - w0s[k]) : 0.0f;
        acc = fmaf(w0, u0[k], acc);
        acc = fmaf(w1, u1[k], acc);
      }
    }
  }
  if (half == 0) sacc[nl][lane] = acc;
  __syncthreads();
  if (half == 1 && valid) {
    float total = acc + sacc[nl][lane];
    float L = b2f(UL[(size_t)i * 576 + 512 + lane]);
    float o = total + L + cb[lane] + fb[lane];
    if (HAS_RES) o += resid[(size_t)i * 64 + lane];
    if (STORE_ANS) outAns[(size_t)i * 64 + lane] = o;
    unsigned short xb = (unsigned short)bf16s(fmaxf(o, 0.0f));
    outAnsc[(size_t)i * 64 + lane] = xb;
    if (COMPUTE_T) {
      // T[i][t] = sum_ch ansc2[i,ch] * cW3[t>>1][ch][t&1], ansc2 read back through bf16
      float x = b2f(xb);
      float c[16];
      #pragma unroll
      for (int t = 0; t < 16; ++t)
        c[t] = x * cW3[((size_t)(t >> 1) * 64 + lane) * 2 + (t & 1)];
      #pragma unroll
      for (int off = 32; off > 0; off >>= 1) {
        #pragma unroll
        for (int t = 0; t < 16; ++t) c[t] += __shfl_xor(c[t], off, 64);
      }
      if (lane == 0) {
        float* tr = T + (size_t)i * 16;
        #pragma unroll
        for (int t = 0; t < 16; ++t) tr[t] = c[t];
      }
    }
  }
}

// ---------- layer 3: wave per node, lane = edge; 16B/edge from T; + lin; reduce ----------
__global__ __launch_bounds__(256, 4) void layer3_kernel(
    const unsigned short* __restrict__ Xb,  // ansc2 [n,64] bf16
    const float* __restrict__ T,            // [n,16] fp32
    const int* __restrict__ cnt, const int* __restrict__ jw,
    const float* __restrict__ cb3, const float* __restrict__ fb3,
    const float* __restrict__ fW3,          // [64,2]
    float* __restrict__ out, int n) {
  const int lane = threadIdx.x & 63;
  const int i = (blockIdx.x * blockDim.x + threadIdx.x) >> 6;
  if (i >= n) return;
  const int m = min(cnt[i], CAP);
  float c0 = 0.0f, c1 = 0.0f;
  if (lane < m) {                      // lane = edge index (fully lane-parallel)
    int v = jw[(size_t)i * CAP + lane];
    int j = min(v & 0x7FFF, n - 1);
    int p = (v >> 15) & 7;
    float w0 = (float)((unsigned)v >> 18) * (1.0f / 16383.0f);
    float w1 = 1.0f - w0;
    const float* tb = T + (size_t)j * 16 + p * 2;
    float2 ta = *(const float2*)(tb);
    float2 tc = *(const float2*)(tb + 2);
    c0 = w0 * ta.x + w1 * tc.x;
    c1 = w0 * ta.y + w1 * tc.y;
  }
  // linear path: lane = channel
  float xi = b2f(Xb[(size_t)i * 64 + lane]);
  float2 fw = *(const float2*)(fW3 + lane * 2);
  c0 = fmaf(xi, fw.x, c0);
  c1 = fmaf(xi, fw.y, c1);
  #pragma unroll
  for (int off = 32; off > 0; off >>= 1) {
    c0 += __shfl_xor(c0, off, 64);
    c1 += __shfl_xor(c1, off, 64);
  }
  if (lane == 0) {
    out[(size_t)i * 2 + 0] = c0 + cb3[0] + fb3[0];
    out[(size_t)i * 2 + 1] = c1 + cb3[1] + fb3[1];
  }
}

extern "C" void kernel_launch(void* const* d_in, const int* in_sizes, int n_in,
                              void* d_out, int out_size, void* d_ws, size_t ws_size,
                              hipStream_t stream) {
  const float* X    = (const float*)d_in[0];
  const int*   fi   = (const int*)d_in[1];
  const int*   fj   = (const int*)d_in[2];
  const float* dist = (const float*)d_in[3];
  const float* cW0 = (const float*)d_in[4];  const float* cb0 = (const float*)d_in[5];
  const float* fW0 = (const float*)d_in[6];  const float* fb0 = (const float*)d_in[7];
  const float* cW1 = (const float*)d_in[8];  const float* cb1 = (const float*)d_in[9];
  const float* fW1 = (const float*)d_in[10]; const float* fb1 = (const float*)d_in[11];
  const float* cW2 = (const float*)d_in[12]; const float* cb2 = (const float*)d_in[13];
  const float* fW2 = (const float*)d_in[14]; const float* fb2 = (const float*)d_in[15];
  const float* cW3 = (const float*)d_in[16]; const float* cb3 = (const float*)d_in[17];
  const float* fW3 = (const float*)d_in[18]; const float* fb3 = (const float*)d_in[19];
  float* out = (float*)d_out;

  const int n  = in_sizes[0] / 4;  // N = 30000
  const int nE = in_sizes[1];      // E = 480000

  // workspace (~58 MB): UL bf16[n*576] | ansc0 bf16[n*64] (alias ansc2) | ansc1 bf16[n*64]
  //   | ans1 fp32[n*64] | T fp32[n*16] | wtul1[576*64] | wtul2 | jw[n*CAP] | cnt[n]
  unsigned short* UL    = (unsigned short*)d_ws;
  unsigned short* ansc0 = UL + (size_t)n * 576;
  unsigned short* ansc1 = ansc0 + (size_t)n * 64;
  float*          ans1  = (float*)(ansc1 + (size_t)n * 64);
  unsigned short* ansc2 = ansc0;            // ansc0 dead after gemm_ul #1
  float* T     = ans1 + (size_t)n * 64;
  short* wtul1 = (short*)(T + (size_t)n * 16);
  short* wtul2 = wtul1 + 576 * 64;
  int*   jw    = (int*)(wtul2 + 576 * 64);
  int*   cnt   = jw + (size_t)n * CAP;

  hipMemsetAsync(cnt, 0, (size_t)n * sizeof(int), stream);
  fill_kernel<<<(nE + 255) / 256, 256, 0, stream>>>(dist, fi, fj, cnt, jw, nE);
  prep_wtul<<<(2 * 576 * 64 + 255) / 256, 256, 0, stream>>>(cW1, fW1, cW2, fW2, wtul1, wtul2);

  // layer 0
  layer0_kernel<<<(n + 3) / 4, 256, 0, stream>>>(X, cnt, jw,
                                                 cW0, cb0, fW0, fb0, ansc0, n);
  // layer 1
  gemm_ul<<<(n + 15) / 16, 256, 0, stream>>>(ansc0, wtul1, UL, n);
  conv_gather<false, true, false><<<(n + 1) / 2, 256, 0, stream>>>(
      UL, cnt, jw, cb1, fb1, nullptr, nullptr, nullptr, ans1, ansc1, n);
  // layer 2 (residual) + fused T for layer 3
  gemm_ul<<<(n + 15) / 16, 256, 0, stream>>>(ansc1, wtul2, UL, n);
  conv_gather<true, false, true><<<(n + 1) / 2, 256, 0, stream>>>(
      UL, cnt, jw, cb2, fb2, ans1, cW3, T, nullptr, ansc2, n);
  // layer 3
  layer3_kernel<<<(n * 64 + 255) / 256, 256, 0, stream>>>(ansc2, T, cnt, jw,
                                                          cb3, fb3, fW3, out, n);
}

// Round 13
// 271.901 us; speedup vs baseline: 1.0481x; 1.0481x over previous
//
#include <hip/hip_runtime.h>

// RbfNet on MI355X — round 13: revert r12's 2-wave split (issue-bound regression:
// 2x16-deep batches issued 32 edge-slots/node vs 23 for 1-wave), keep fused T.
// conv_gather: 1 wave/node, 16-deep batches, wave-uniform scalar base addressing
// (saddr+voffset loads, no per-lane 64-bit addr arith), hoisted L/resid loads.
// Structure from r11: UL[j] = [x_j @ cW (p-major, 512) | x_j @ fW (64)] dense MFMA GEMM,
// then conv(x)[i] = sum_e w0*U[j,p] + w1*U[j,p+1]  (2 loads + 2 FMA per edge).
// Edge record (4B): j(15b) | p(3b) | round(w0*16383)(14b); w1 = 1-w0. Self-edges dropped.

#define CAP 48

typedef __attribute__((ext_vector_type(8))) short short8;
typedef __attribute__((ext_vector_type(4))) short short4v;
typedef __attribute__((ext_vector_type(4))) float f32x4;

__device__ __forceinline__ short bf16s(float f) {   // fp32 -> bf16 RNE
  unsigned u = __float_as_uint(f);
  return (short)((u + 0x7FFF + ((u >> 16) & 1)) >> 16);
}
__device__ __forceinline__ float b2f(unsigned short s) {
  return __uint_as_float(((unsigned)s) << 16);
}

// ---------- edge-bucket build ----------
__global__ void fill_kernel(const float* __restrict__ dist,
                            const int* __restrict__ fi, const int* __restrict__ fj,
                            int* __restrict__ cnt, int* __restrict__ jw, int nE) {
  int e = blockIdx.x * blockDim.x + threadIdx.x;
  if (e >= nE) return;
  int i = fi[e], j = fj[e];
  if (i == j) return;                    // centerIgnore
  float d = fminf(1.0f, fmaxf(-1.0f, dist[e]));
  float u = (d + 1.0f) * 3.5f;           // hat centers: spacing 2/7
  int p = min((int)u, 6);
  float w0 = 1.0f - (u - (float)p);
  int wq = (int)(w0 * 16383.0f + 0.5f);
  int pos = atomicAdd(&cnt[i], 1);
  if (pos < CAP)
    jw[(size_t)i * CAP + pos] = j | (p << 15) | (wq << 18);
}

// ---------- prep: WTul[col][ch] bf16; col<512: cW[p=col>>6][ch][co=col&63]; col>=512: fW[ch][col-512]
__global__ void prep_wtul(const float* __restrict__ cW1, const float* __restrict__ fW1,
                          const float* __restrict__ cW2, const float* __restrict__ fW2,
                          short* __restrict__ wt1, short* __restrict__ wt2) {
  int idx = blockIdx.x * blockDim.x + threadIdx.x;
  if (idx >= 2 * 576 * 64) return;
  int sel = idx / (576 * 64);
  int r = idx - sel * (576 * 64);
  int col = r >> 6, ch = r & 63;
  const float* cW = sel ? cW2 : cW1;
  const float* fW = sel ? fW2 : fW1;
  float v;
  if (col < 512) {
    int p = col >> 6, co = col & 63;
    v = cW[((size_t)p * 64 + ch) * 64 + co];
  } else {
    v = fW[(size_t)ch * 64 + (col - 512)];
  }
  (sel ? wt2 : wt1)[(size_t)col * 64 + ch] = bf16s(v);
}

// ---------- layer 0: wave per node, lane-parallel edges, LDS fp32 atomics ----------
__global__ __launch_bounds__(256) void layer0_kernel(
    const float* __restrict__ X,      // [n,4] fp32
    const int* __restrict__ cnt, const int* __restrict__ jw,
    const float* __restrict__ cW0,    // [8*4*32]
    const float* __restrict__ cb0,
    const float* __restrict__ fW0,    // [4*32]
    const float* __restrict__ fb0,
    unsigned short* __restrict__ ansc0, int n) {    // [n,64] bf16 out
  __shared__ float sW[1024];
  __shared__ float sF[128];
  __shared__ float sB[64];
  __shared__ float sacc[4][32];
  for (int idx = threadIdx.x; idx < 1024; idx += 256) sW[idx] = cW0[idx];
  for (int idx = threadIdx.x; idx < 128; idx += 256) sF[idx] = fW0[idx];
  if (threadIdx.x < 32) sB[threadIdx.x] = cb0[threadIdx.x];
  else if (threadIdx.x < 64) sB[threadIdx.x] = fb0[threadIdx.x - 32];
  const int w = threadIdx.x >> 6;
  const int lane = threadIdx.x & 63;
  const int i = blockIdx.x * 4 + w;
  const bool valid = (i < n);
  if (valid && lane < 32) sacc[w][lane] = 0.0f;
  __syncthreads();
  if (valid && lane < min(cnt[i], CAP)) {   // lane = edge index
    int v = jw[(size_t)i * CAP + lane];
    int j = v & 0x7FFF;
    int p = (v >> 15) & 7;
    float w0 = (float)((unsigned)v >> 18) * (1.0f / 16383.0f);
    float w1 = 1.0f - w0;
    float4 x = *(const float4*)(X + (size_t)j * 4);
    atomicAdd(&sacc[w][p * 4 + 0], w0 * x.x);
    atomicAdd(&sacc[w][p * 4 + 1], w0 * x.y);
    atomicAdd(&sacc[w][p * 4 + 2], w0 * x.z);
    atomicAdd(&sacc[w][p * 4 + 3], w0 * x.w);
    atomicAdd(&sacc[w][(p + 1) * 4 + 0], w1 * x.x);
    atomicAdd(&sacc[w][(p + 1) * 4 + 1], w1 * x.y);
    atomicAdd(&sacc[w][(p + 1) * 4 + 2], w1 * x.z);
    atomicAdd(&sacc[w][(p + 1) * 4 + 3], w1 * x.w);
  }
  __syncthreads();
  if (!valid) return;
  const float4 xi = *(const float4*)(X + (size_t)i * 4);
  float v;
  if (lane < 32) {                    // lin -> channels 0..31
    v = sB[32 + lane];
    v = fmaf(xi.x, sF[0 * 32 + lane], v);
    v = fmaf(xi.y, sF[1 * 32 + lane], v);
    v = fmaf(xi.z, sF[2 * 32 + lane], v);
    v = fmaf(xi.w, sF[3 * 32 + lane], v);
  } else {                            // conv -> channels 32..63
    const int cc = lane - 32;
    v = sB[cc];
    #pragma unroll
    for (int k = 0; k < 32; ++k)
      v = fmaf(sacc[w][k], sW[k * 32 + cc], v);
  }
  ansc0[(size_t)i * 64 + lane] = (unsigned short)bf16s(fmaxf(v, 0.0f));
}

// ---------- dense MFMA GEMM: UL[n,576] = Xb[n,64] @ WTul^T ----------
__global__ __launch_bounds__(256) void gemm_ul(
    const unsigned short* __restrict__ Xb,  // [n,64] bf16
    const short* __restrict__ WTul,         // [576,64] bf16 (L2-resident)
    unsigned short* __restrict__ UL, int n) {
  __shared__ short sUL[16 * 584];
  const int lane = threadIdx.x & 63;
  const int w = threadIdx.x >> 6;
  const int mrow = lane & 15;
  const int quad = lane >> 4;
  const int nodeBase = blockIdx.x * 16;
  const int bnode = min(nodeBase + mrow, n - 1);
  const unsigned short* bBase = Xb + (size_t)bnode * 64 + quad * 8;
  short8 b0 = *(const short8*)(bBase);
  short8 b1 = *(const short8*)(bBase + 32);
  #pragma unroll
  for (int t = 0; t < 9; ++t) {
    const int ct = w * 9 + t;
    const short* aBase = WTul + (size_t)(ct * 16 + mrow) * 64 + quad * 8;
    short8 a0 = *(const short8*)(aBase);
    short8 a1 = *(const short8*)(aBase + 32);
    f32x4 acc = {0, 0, 0, 0};
    acc = __builtin_amdgcn_mfma_f32_16x16x32_bf16(a0, b0, acc, 0, 0, 0);
    acc = __builtin_amdgcn_mfma_f32_16x16x32_bf16(a1, b1, acc, 0, 0, 0);
    short4v pk;
    #pragma unroll
    for (int reg = 0; reg < 4; ++reg) pk[reg] = bf16s(acc[reg]);
    *(short4v*)(sUL + mrow * 584 + ct * 16 + quad * 4) = pk;
  }
  __syncthreads();
  const int r = threadIdx.x >> 4;
  const int c0 = threadIdx.x & 15;
  if (nodeBase + r < n) {
    unsigned short* dst = UL + (size_t)(nodeBase + r) * 576;
    #pragma unroll
    for (int chunk = c0; chunk < 72; chunk += 16)
      *(short8*)(dst + chunk * 8) = *(const short8*)(sUL + r * 584 + chunk * 8);
  }
}

// ---------- conv gather: wave per node; per edge 2 loads + 2 FMA (scalar base addr) ----------
template <bool HAS_RES, bool STORE_ANS, bool COMPUTE_T>
__global__ __launch_bounds__(256) void conv_gather(
    const unsigned short* __restrict__ UL,  // [n,576] bf16
    const int* __restrict__ cnt, const int* __restrict__ jw,
    const float* __restrict__ cb, const float* __restrict__ fb,
    const float* __restrict__ resid,        // fp32 [n,64] or null
    const float* __restrict__ cW3,          // [8,64,2] (only if COMPUTE_T)
    float* __restrict__ T,                  // [n,16] fp32 (only if COMPUTE_T)
    float* __restrict__ outAns,             // fp32 [n,64] or null
    unsigned short* __restrict__ outAnsc, int n) {  // bf16 [n,64]
  const int lane = threadIdx.x & 63;
  const int i = (blockIdx.x * blockDim.x + threadIdx.x) >> 6;
  if (i >= n) return;
  int rec = jw[(size_t)i * CAP + (lane < CAP ? lane : 0)];  // lane q holds record q
  const int m = min(cnt[i], CAP);
  // hoisted epilogue loads (issue early, overlap with edge loop)
  float L = b2f(UL[(size_t)i * 576 + 512 + lane]);
  float rv = HAS_RES ? resid[(size_t)i * 64 + lane] : 0.0f;
  float acc = 0.0f;
  for (int q0 = 0; q0 < m; q0 += 16) {
    float u0[16], u1[16], w0s[16];
    #pragma unroll
    for (int k = 0; k < 16; ++k) {          // issue all 32 loads before consuming
      int v = __builtin_amdgcn_readlane(rec, q0 + k);
      int j = min(v & 0x7FFF, n - 1);       // clamp garbage slots in-bounds
      int p = (v >> 15) & 7;
      w0s[k] = (float)((unsigned)v >> 18) * (1.0f / 16383.0f);
      const unsigned short* sbase = UL + (size_t)j * 576 + p * 64;  // wave-uniform
      u0[k] = b2f(sbase[lane]);
      u1[k] = b2f(sbase[lane + 64]);
    }
    #pragma unroll
    for (int k = 0; k < 16; ++k) {
      bool ok = (q0 + k < m);
      float w0 = ok ? w0s[k] : 0.0f;
      float w1 = ok ? (1.0f - w0s[k]) : 0.0f;
      acc = fmaf(w0, u0[k], acc);
      acc = fmaf(w1, u1[k], acc);
    }
  }
  float o = acc + L + cb[lane] + fb[lane] + rv;
  if (STORE_ANS) outAns[(size_t)i * 64 + lane] = o;
  unsigned short xb = (unsigned short)bf16s(fmaxf(o, 0.0f));
  outAnsc[(size_t)i * 64 + lane] = xb;
  if (COMPUTE_T) {
    // T[i][t] = sum_ch ansc2[i,ch] * cW3[t>>1][ch][t&1], ansc2 read back through bf16
    float x = b2f(xb);
    float c[16];
    #pragma unroll
    for (int t = 0; t < 16; ++t)
      c[t] = x * cW3[((size_t)(t >> 1) * 64 + lane) * 2 + (t & 1)];
    #pragma unroll
    for (int off = 32; off > 0; off >>= 1) {
      #pragma unroll
      for (int t = 0; t < 16; ++t) c[t] += __shfl_xor(c[t], off, 64);
    }
    if (lane == 0) {
      float* tr = T + (size_t)i * 16;
      #pragma unroll
      for (int t = 0; t < 16; ++t) tr[t] = c[t];
    }
  }
}

// ---------- layer 3: wave per node, lane = edge; 16B/edge from T; + lin; reduce ----------
__global__ __launch_bounds__(256, 4) void layer3_kernel(
    const unsigned short* __restrict__ Xb,  // ansc2 [n,64] bf16
    const float* __restrict__ T,            // [n,16] fp32
    const int* __restrict__ cnt, const int* __restrict__ jw,
    const float* __restrict__ cb3, const float* __restrict__ fb3,
    const float* __restrict__ fW3,          // [64,2]
    float* __restrict__ out, int n) {
  const int lane = threadIdx.x & 63;
  const int i = (blockIdx.x * blockDim.x + threadIdx.x) >> 6;
  if (i >= n) return;
  const int m = min(cnt[i], CAP);
  float c0 = 0.0f, c1 = 0.0f;
  if (lane < m) {                      // lane = edge index (fully lane-parallel)
    int v = jw[(size_t)i * CAP + lane];
    int j = min(v & 0x7FFF, n - 1);
    int p = (v >> 15) & 7;
    float w0 = (float)((unsigned)v >> 18) * (1.0f / 16383.0f);
    float w1 = 1.0f - w0;
    const float* tb = T + (size_t)j * 16 + p * 2;
    float2 ta = *(const float2*)(tb);
    float2 tc = *(const float2*)(tb + 2);
    c0 = w0 * ta.x + w1 * tc.x;
    c1 = w0 * ta.y + w1 * tc.y;
  }
  // linear path: lane = channel
  float xi = b2f(Xb[(size_t)i * 64 + lane]);
  float2 fw = *(const float2*)(fW3 + lane * 2);
  c0 = fmaf(xi, fw.x, c0);
  c1 = fmaf(xi, fw.y, c1);
  #pragma unroll
  for (int off = 32; off > 0; off >>= 1) {
    c0 += __shfl_xor(c0, off, 64);
    c1 += __shfl_xor(c1, off, 64);
  }
  if (lane == 0) {
    out[(size_t)i * 2 + 0] = c0 + cb3[0] + fb3[0];
    out[(size_t)i * 2 + 1] = c1 + cb3[1] + fb3[1];
  }
}

extern "C" void kernel_launch(void* const* d_in, const int* in_sizes, int n_in,
                              void* d_out, int out_size, void* d_ws, size_t ws_size,
                              hipStream_t stream) {
  const float* X    = (const float*)d_in[0];
  const int*   fi   = (const int*)d_in[1];
  const int*   fj   = (const int*)d_in[2];
  const float* dist = (const float*)d_in[3];
  const float* cW0 = (const float*)d_in[4];  const float* cb0 = (const float*)d_in[5];
  const float* fW0 = (const float*)d_in[6];  const float* fb0 = (const float*)d_in[7];
  const float* cW1 = (const float*)d_in[8];  const float* cb1 = (const float*)d_in[9];
  const float* fW1 = (const float*)d_in[10]; const float* fb1 = (const float*)d_in[11];
  const float* cW2 = (const float*)d_in[12]; const float* cb2 = (const float*)d_in[13];
  const float* fW2 = (const float*)d_in[14]; const float* fb2 = (const float*)d_in[15];
  const float* cW3 = (const float*)d_in[16]; const float* cb3 = (const float*)d_in[17];
  const float* fW3 = (const float*)d_in[18]; const float* fb3 = (const float*)d_in[19];
  float* out = (float*)d_out;

  const int n  = in_sizes[0] / 4;  // N = 30000
  const int nE = in_sizes[1];      // E = 480000

  // workspace (~58 MB): UL bf16[n*576] | ansc0 bf16[n*64] (alias ansc2) | ansc1 bf16[n*64]
  //   | ans1 fp32[n*64] | T fp32[n*16] | wtul1[576*64] | wtul2 | jw[n*CAP] | cnt[n]
  unsigned short* UL    = (unsigned short*)d_ws;
  unsigned short* ansc0 = UL + (size_t)n * 576;
  unsigned short* ansc1 = ansc0 + (size_t)n * 64;
  float*          ans1  = (float*)(ansc1 + (size_t)n * 64);
  unsigned short* ansc2 = ansc0;            // ansc0 dead after gemm_ul #1
  float* T     = ans1 + (size_t)n * 64;
  short* wtul1 = (short*)(T + (size_t)n * 16);
  short* wtul2 = wtul1 + 576 * 64;
  int*   jw    = (int*)(wtul2 + 576 * 64);
  int*   cnt   = jw + (size_t)n * CAP;

  hipMemsetAsync(cnt, 0, (size_t)n * sizeof(int), stream);
  fill_kernel<<<(nE + 255) / 256, 256, 0, stream>>>(dist, fi, fj, cnt, jw, nE);
  prep_wtul<<<(2 * 576 * 64 + 255) / 256, 256, 0, stream>>>(cW1, fW1, cW2, fW2, wtul1, wtul2);

  // layer 0
  layer0_kernel<<<(n + 3) / 4, 256, 0, stream>>>(X, cnt, jw,
                                                 cW0, cb0, fW0, fb0, ansc0, n);
  // layer 1
  gemm_ul<<<(n + 15) / 16, 256, 0, stream>>>(ansc0, wtul1, UL, n);
  conv_gather<false, true, false><<<(n * 64 + 255) / 256, 256, 0, stream>>>(
      UL, cnt, jw, cb1, fb1, nullptr, nullptr, nullptr, ans1, ansc1, n);
  // layer 2 (residual) + fused T for layer 3
  gemm_ul<<<(n + 15) / 16, 256, 0, stream>>>(ansc1, wtul2, UL, n);
  conv_gather<true, false, true><<<(n * 64 + 255) / 256, 256, 0, stream>>>(
      UL, cnt, jw, cb2, fb2, ans1, cW3, T, nullptr, ansc2, n);
  // layer 3
  layer3_kernel<<<(n * 64 + 255) / 256, 256, 0, stream>>>(ansc2, T, cnt, jw,
                                                          cb3, fb3, fW3, out, n);
}

// Round 14
// 270.207 us; speedup vs baseline: 1.0546x; 1.0063x over previous
//
#include <hip/hip_runtime.h>

// RbfNet on MI355X — round 14: pair-packed conv_gather.
// U[j,p] and U[j,p+1] are ADJACENT 128B spans in the UL row -> one uint/lane load
// covers both (lanes 0-31 = u0 channel-pairs, lanes 32-63 = u1 pairs). 1 VMEM/edge
// (was 2), half the in-flight batch registers; shfl_xor(32) merges halves at the end.
// Also: prep_wtul merged into fill_kernel (block-range split) — one fewer launch.
// Structure: UL[j] = [x_j @ cW (p-major, 512) | x_j @ fW (64)] dense MFMA GEMM, then
// conv(x)[i] = sum_e w0*U[j,p] + w1*U[j,p+1]; layer3 via T[j][p] = ansc2[j] @ cW3[p].
// Edge record (4B): j(15b) | p(3b) | round(w0*16383)(14b); w1 = 1-w0. Self-edges dropped.

#define CAP 48

typedef __attribute__((ext_vector_type(8))) short short8;
typedef __attribute__((ext_vector_type(4))) short short4v;
typedef __attribute__((ext_vector_type(4))) float f32x4;

__device__ __forceinline__ short bf16s(float f) {   // fp32 -> bf16 RNE
  unsigned u = __float_as_uint(f);
  return (short)((u + 0x7FFF + ((u >> 16) & 1)) >> 16);
}
__device__ __forceinline__ float b2f(unsigned short s) {
  return __uint_as_float(((unsigned)s) << 16);
}

// ---------- fused: edge-bucket build (blocks < fillBlocks) + WTul prep (rest) ----------
// WTul[col][ch]: col<512 -> cW[p=col>>6][ch][co=col&63]; col>=512 -> fW[ch][col-512]
__global__ void fill_prep(const float* __restrict__ dist,
                          const int* __restrict__ fi, const int* __restrict__ fj,
                          int* __restrict__ cnt, int* __restrict__ jw, int nE,
                          const float* __restrict__ cW1, const float* __restrict__ fW1,
                          const float* __restrict__ cW2, const float* __restrict__ fW2,
                          short* __restrict__ wt1, short* __restrict__ wt2,
                          int fillBlocks) {
  if ((int)blockIdx.x < fillBlocks) {
    int e = blockIdx.x * blockDim.x + threadIdx.x;
    if (e >= nE) return;
    int i = fi[e], j = fj[e];
    if (i == j) return;                  // centerIgnore
    float d = fminf(1.0f, fmaxf(-1.0f, dist[e]));
    float u = (d + 1.0f) * 3.5f;         // hat centers: spacing 2/7
    int p = min((int)u, 6);
    float w0 = 1.0f - (u - (float)p);
    int wq = (int)(w0 * 16383.0f + 0.5f);
    int pos = atomicAdd(&cnt[i], 1);
    if (pos < CAP)
      jw[(size_t)i * CAP + pos] = j | (p << 15) | (wq << 18);
  } else {
    int idx = ((int)blockIdx.x - fillBlocks) * blockDim.x + threadIdx.x;
    if (idx >= 2 * 576 * 64) return;
    int sel = idx / (576 * 64);
    int r = idx - sel * (576 * 64);
    int col = r >> 6, ch = r & 63;
    const float* cW = sel ? cW2 : cW1;
    const float* fW = sel ? fW2 : fW1;
    float v;
    if (col < 512) {
      int p = col >> 6, co = col & 63;
      v = cW[((size_t)p * 64 + ch) * 64 + co];
    } else {
      v = fW[(size_t)ch * 64 + (col - 512)];
    }
    (sel ? wt2 : wt1)[(size_t)col * 64 + ch] = bf16s(v);
  }
}

// ---------- layer 0: wave per node, lane-parallel edges, LDS fp32 atomics ----------
__global__ __launch_bounds__(256) void layer0_kernel(
    const float* __restrict__ X,      // [n,4] fp32
    const int* __restrict__ cnt, const int* __restrict__ jw,
    const float* __restrict__ cW0,    // [8*4*32]
    const float* __restrict__ cb0,
    const float* __restrict__ fW0,    // [4*32]
    const float* __restrict__ fb0,
    unsigned short* __restrict__ ansc0, int n) {    // [n,64] bf16 out
  __shared__ float sW[1024];
  __shared__ float sF[128];
  __shared__ float sB[64];
  __shared__ float sacc[4][32];
  for (int idx = threadIdx.x; idx < 1024; idx += 256) sW[idx] = cW0[idx];
  for (int idx = threadIdx.x; idx < 128; idx += 256) sF[idx] = fW0[idx];
  if (threadIdx.x < 32) sB[threadIdx.x] = cb0[threadIdx.x];
  else if (threadIdx.x < 64) sB[threadIdx.x] = fb0[threadIdx.x - 32];
  const int w = threadIdx.x >> 6;
  const int lane = threadIdx.x & 63;
  const int i = blockIdx.x * 4 + w;
  const bool valid = (i < n);
  if (valid && lane < 32) sacc[w][lane] = 0.0f;
  __syncthreads();
  if (valid && lane < min(cnt[i], CAP)) {   // lane = edge index
    int v = jw[(size_t)i * CAP + lane];
    int j = v & 0x7FFF;
    int p = (v >> 15) & 7;
    float w0 = (float)((unsigned)v >> 18) * (1.0f / 16383.0f);
    float w1 = 1.0f - w0;
    float4 x = *(const float4*)(X + (size_t)j * 4);
    atomicAdd(&sacc[w][p * 4 + 0], w0 * x.x);
    atomicAdd(&sacc[w][p * 4 + 1], w0 * x.y);
    atomicAdd(&sacc[w][p * 4 + 2], w0 * x.z);
    atomicAdd(&sacc[w][p * 4 + 3], w0 * x.w);
    atomicAdd(&sacc[w][(p + 1) * 4 + 0], w1 * x.x);
    atomicAdd(&sacc[w][(p + 1) * 4 + 1], w1 * x.y);
    atomicAdd(&sacc[w][(p + 1) * 4 + 2], w1 * x.z);
    atomicAdd(&sacc[w][(p + 1) * 4 + 3], w1 * x.w);
  }
  __syncthreads();
  if (!valid) return;
  const float4 xi = *(const float4*)(X + (size_t)i * 4);
  float v;
  if (lane < 32) {                    // lin -> channels 0..31
    v = sB[32 + lane];
    v = fmaf(xi.x, sF[0 * 32 + lane], v);
    v = fmaf(xi.y, sF[1 * 32 + lane], v);
    v = fmaf(xi.z, sF[2 * 32 + lane], v);
    v = fmaf(xi.w, sF[3 * 32 + lane], v);
  } else {                            // conv -> channels 32..63
    const int cc = lane - 32;
    v = sB[cc];
    #pragma unroll
    for (int k = 0; k < 32; ++k)
      v = fmaf(sacc[w][k], sW[k * 32 + cc], v);
  }
  ansc0[(size_t)i * 64 + lane] = (unsigned short)bf16s(fmaxf(v, 0.0f));
}

// ---------- dense MFMA GEMM: UL[n,576] = Xb[n,64] @ WTul^T ----------
__global__ __launch_bounds__(256) void gemm_ul(
    const unsigned short* __restrict__ Xb,  // [n,64] bf16
    const short* __restrict__ WTul,         // [576,64] bf16 (L2-resident)
    unsigned short* __restrict__ UL, int n) {
  __shared__ short sUL[16 * 584];
  const int lane = threadIdx.x & 63;
  const int w = threadIdx.x >> 6;
  const int mrow = lane & 15;
  const int quad = lane >> 4;
  const int nodeBase = blockIdx.x * 16;
  const int bnode = min(nodeBase + mrow, n - 1);
  const unsigned short* bBase = Xb + (size_t)bnode * 64 + quad * 8;
  short8 b0 = *(const short8*)(bBase);
  short8 b1 = *(const short8*)(bBase + 32);
  #pragma unroll
  for (int t = 0; t < 9; ++t) {
    const int ct = w * 9 + t;
    const short* aBase = WTul + (size_t)(ct * 16 + mrow) * 64 + quad * 8;
    short8 a0 = *(const short8*)(aBase);
    short8 a1 = *(const short8*)(aBase + 32);
    f32x4 acc = {0, 0, 0, 0};
    acc = __builtin_amdgcn_mfma_f32_16x16x32_bf16(a0, b0, acc, 0, 0, 0);
    acc = __builtin_amdgcn_mfma_f32_16x16x32_bf16(a1, b1, acc, 0, 0, 0);
    short4v pk;
    #pragma unroll
    for (int reg = 0; reg < 4; ++reg) pk[reg] = bf16s(acc[reg]);
    *(short4v*)(sUL + mrow * 584 + ct * 16 + quad * 4) = pk;
  }
  __syncthreads();
  const int r = threadIdx.x >> 4;
  const int c0 = threadIdx.x & 15;
  if (nodeBase + r < n) {
    unsigned short* dst = UL + (size_t)(nodeBase + r) * 576;
    #pragma unroll
    for (int chunk = c0; chunk < 72; chunk += 16)
      *(short8*)(dst + chunk * 8) = *(const short8*)(sUL + r * 584 + chunk * 8);
  }
}

// ---------- conv gather: wave per node; ONE uint load per edge (256B span = u0|u1) ----------
// lanes 0-31: u0 channel-pairs (w0); lanes 32-63: u1 pairs (w1). shfl_xor(32) merges.
template <bool HAS_RES, bool STORE_ANS, bool COMPUTE_T>
__global__ __launch_bounds__(256) void conv_gather(
    const unsigned short* __restrict__ UL,  // [n,576] bf16
    const int* __restrict__ cnt, const int* __restrict__ jw,
    const float* __restrict__ cb, const float* __restrict__ fb,
    const float* __restrict__ resid,        // fp32 [n,64] or null
    const float* __restrict__ cW3,          // [8,64,2] (only if COMPUTE_T)
    float* __restrict__ T,                  // [n,16] fp32 (only if COMPUTE_T)
    float* __restrict__ outAns,             // fp32 [n,64] or null
    unsigned short* __restrict__ outAnsc, int n) {  // bf16 [n,64]
  const int lane = threadIdx.x & 63;
  const int half = lane >> 5;               // 0 -> u0 (w0), 1 -> u1 (w1)
  const int pl = lane & 31;                 // channel-pair index
  const int i = (blockIdx.x * blockDim.x + threadIdx.x) >> 6;
  if (i >= n) return;
  int rec = jw[(size_t)i * CAP + (lane < CAP ? lane : 0)];  // lane q holds record q
  const int m = min(cnt[i], CAP);
  // hoisted epilogue loads (overlap with edge loop); both halves load same addrs (cached)
  const unsigned short* ULrow = UL + (size_t)i * 576;
  const unsigned Lraw = ((const unsigned*)(ULrow + 512))[pl];
  float rv0 = 0.0f, rv1 = 0.0f;
  if (HAS_RES) {
    float2 rv = *(const float2*)(resid + (size_t)i * 64 + 2 * pl);
    rv0 = rv.x; rv1 = rv.y;
  }
  float accLo = 0.0f, accHi = 0.0f;         // channels 2*pl, 2*pl+1 of this half
  for (int q0 = 0; q0 < m; q0 += 16) {
    unsigned raw[16];
    float w0s[16];
    #pragma unroll
    for (int k = 0; k < 16; ++k) {          // issue all 16 loads before consuming
      int v = __builtin_amdgcn_readlane(rec, q0 + k);
      int j = min(v & 0x7FFF, n - 1);       // clamp garbage slots in-bounds
      int p = (v >> 15) & 7;
      w0s[k] = (float)((unsigned)v >> 18) * (1.0f / 16383.0f);
      // 256B span: u0 (128B) || u1 (128B); lane*4B covers both halves
      raw[k] = ((const unsigned*)(UL + (size_t)j * 576 + p * 64))[lane];
    }
    #pragma unroll
    for (int k = 0; k < 16; ++k) {
      bool ok = (q0 + k < m);
      float w = half ? (1.0f - w0s[k]) : w0s[k];
      w = ok ? w : 0.0f;
      float lo = __uint_as_float(raw[k] << 16);
      float hi = __uint_as_float(raw[k] & 0xFFFF0000u);
      accLo = fmaf(w, lo, accLo);
      accHi = fmaf(w, hi, accHi);
    }
  }
  accLo += __shfl_xor(accLo, 32, 64);       // merge u0/u1 halves
  accHi += __shfl_xor(accHi, 32, 64);
  if (half == 0) {                          // lanes 0-31 do the epilogue
    const int c0i = 2 * pl, c1i = c0i + 1;
    float L0 = __uint_as_float(Lraw << 16);
    float L1 = __uint_as_float(Lraw & 0xFFFF0000u);
    float o0 = accLo + L0 + cb[c0i] + fb[c0i] + rv0;
    float o1 = accHi + L1 + cb[c1i] + fb[c1i] + rv1;
    if (STORE_ANS)
      *(float2*)(outAns + (size_t)i * 64 + c0i) = make_float2(o0, o1);
    unsigned short xb0 = (unsigned short)bf16s(fmaxf(o0, 0.0f));
    unsigned short xb1 = (unsigned short)bf16s(fmaxf(o1, 0.0f));
    ((unsigned*)(outAnsc + (size_t)i * 64))[pl] = (unsigned)xb0 | ((unsigned)xb1 << 16);
    if (COMPUTE_T) {
      // T[i][t] = sum_ch ansc2[i,ch] * cW3[t>>1][ch][t&1], ansc2 read back through bf16
      float x0 = b2f(xb0), x1 = b2f(xb1);
      float c[16];
      #pragma unroll
      for (int t = 0; t < 16; ++t) {
        const float* wrow = cW3 + ((size_t)(t >> 1) * 64) * 2 + (t & 1);
        c[t] = x0 * wrow[c0i * 2] + x1 * wrow[c1i * 2];
      }
      #pragma unroll
      for (int off = 16; off > 0; off >>= 1) {   // butterfly within lanes 0-31
        #pragma unroll
        for (int t = 0; t < 16; ++t) c[t] += __shfl_xor(c[t], off, 64);
      }
      if (pl == 0) {
        float* tr = T + (size_t)i * 16;
        #pragma unroll
        for (int t = 0; t < 16; ++t) tr[t] = c[t];
      }
    }
  }
}

// ---------- layer 3: wave per node, lane = edge; 16B/edge from T; + lin; reduce ----------
__global__ __launch_bounds__(256, 4) void layer3_kernel(
    const unsigned short* __restrict__ Xb,  // ansc2 [n,64] bf16
    const float* __restrict__ T,            // [n,16] fp32
    const int* __restrict__ cnt, const int* __restrict__ jw,
    const float* __restrict__ cb3, const float* __restrict__ fb3,
    const float* __restrict__ fW3,          // [64,2]
    float* __restrict__ out, int n) {
  const int lane = threadIdx.x & 63;
  const int i = (blockIdx.x * blockDim.x + threadIdx.x) >> 6;
  if (i >= n) return;
  const int m = min(cnt[i], CAP);
  float c0 = 0.0f, c1 = 0.0f;
  if (lane < m) {                      // lane = edge index (fully lane-parallel)
    int v = jw[(size_t)i * CAP + lane];
    int j = min(v & 0x7FFF, n - 1);
    int p = (v >> 15) & 7;
    float w0 = (float)((unsigned)v >> 18) * (1.0f / 16383.0f);
    float w1 = 1.0f - w0;
    const float* tb = T + (size_t)j * 16 + p * 2;
    float2 ta = *(const float2*)(tb);
    float2 tc = *(const float2*)(tb + 2);
    c0 = w0 * ta.x + w1 * tc.x;
    c1 = w0 * ta.y + w1 * tc.y;
  }
  // linear path: lane = channel
  float xi = b2f(Xb[(size_t)i * 64 + lane]);
  float2 fw = *(const float2*)(fW3 + lane * 2);
  c0 = fmaf(xi, fw.x, c0);
  c1 = fmaf(xi, fw.y, c1);
  #pragma unroll
  for (int off = 32; off > 0; off >>= 1) {
    c0 += __shfl_xor(c0, off, 64);
    c1 += __shfl_xor(c1, off, 64);
  }
  if (lane == 0) {
    out[(size_t)i * 2 + 0] = c0 + cb3[0] + fb3[0];
    out[(size_t)i * 2 + 1] = c1 + cb3[1] + fb3[1];
  }
}

extern "C" void kernel_launch(void* const* d_in, const int* in_sizes, int n_in,
                              void* d_out, int out_size, void* d_ws, size_t ws_size,
                              hipStream_t stream) {
  const float* X    = (const float*)d_in[0];
  const int*   fi   = (const int*)d_in[1];
  const int*   fj   = (const int*)d_in[2];
  const float* dist = (const float*)d_in[3];
  const float* cW0 = (const float*)d_in[4];  const float* cb0 = (const float*)d_in[5];
  const float* fW0 = (const float*)d_in[6];  const float* fb0 = (const float*)d_in[7];
  const float* cW1 = (const float*)d_in[8];  const float* cb1 = (const float*)d_in[9];
  const float* fW1 = (const float*)d_in[10]; const float* fb1 = (const float*)d_in[11];
  const float* cW2 = (const float*)d_in[12]; const float* cb2 = (const float*)d_in[13];
  const float* fW2 = (const float*)d_in[14]; const float* fb2 = (const float*)d_in[15];
  const float* cW3 = (const float*)d_in[16]; const float* cb3 = (const float*)d_in[17];
  const float* fW3 = (const float*)d_in[18]; const float* fb3 = (const float*)d_in[19];
  float* out = (float*)d_out;

  const int n  = in_sizes[0] / 4;  // N = 30000
  const int nE = in_sizes[1];      // E = 480000

  // workspace (~58 MB): UL bf16[n*576] | ansc0 bf16[n*64] (alias ansc2) | ansc1 bf16[n*64]
  //   | ans1 fp32[n*64] | T fp32[n*16] | wtul1[576*64] | wtul2 | jw[n*CAP] | cnt[n]
  unsigned short* UL    = (unsigned short*)d_ws;
  unsigned short* ansc0 = UL + (size_t)n * 576;
  unsigned short* ansc1 = ansc0 + (size_t)n * 64;
  float*          ans1  = (float*)(ansc1 + (size_t)n * 64);
  unsigned short* ansc2 = ansc0;            // ansc0 dead after gemm_ul #1
  float* T     = ans1 + (size_t)n * 64;
  short* wtul1 = (short*)(T + (size_t)n * 16);
  short* wtul2 = wtul1 + 576 * 64;
  int*   jw    = (int*)(wtul2 + 576 * 64);
  int*   cnt   = jw + (size_t)n * CAP;

  hipMemsetAsync(cnt, 0, (size_t)n * sizeof(int), stream);
  const int fillBlocks = (nE + 255) / 256;
  const int prepBlocks = (2 * 576 * 64 + 255) / 256;
  fill_prep<<<fillBlocks + prepBlocks, 256, 0, stream>>>(
      dist, fi, fj, cnt, jw, nE, cW1, fW1, cW2, fW2, wtul1, wtul2, fillBlocks);

  // layer 0
  layer0_kernel<<<(n + 3) / 4, 256, 0, stream>>>(X, cnt, jw,
                                                 cW0, cb0, fW0, fb0, ansc0, n);
  // layer 1
  gemm_ul<<<(n + 15) / 16, 256, 0, stream>>>(ansc0, wtul1, UL, n);
  conv_gather<false, true, false><<<(n * 64 + 255) / 256, 256, 0, stream>>>(
      UL, cnt, jw, cb1, fb1, nullptr, nullptr, nullptr, ans1, ansc1, n);
  // layer 2 (residual) + fused T for layer 3
  gemm_ul<<<(n + 15) / 16, 256, 0, stream>>>(ansc1, wtul2, UL, n);
  conv_gather<true, false, true><<<(n * 64 + 255) / 256, 256, 0, stream>>>(
      UL, cnt, jw, cb2, fb2, ans1, cW3, T, nullptr, ansc2, n);
  // layer 3
  layer3_kernel<<<(n * 64 + 255) / 256, 256, 0, stream>>>(ansc2, T, cnt, jw,
                                                          cb3, fb3, fW3, out, n);
}